// Round 1
// baseline (29666.763 us; speedup 1.0000x reference)
//
#include <hip/hip_runtime.h>
#include <math.h>

// DNC forward, fully fused: 1 block per batch element, T-loop inside kernel,
// all recurrent state in LDS. fp32 end-to-end.

#define TT   64
#define BB   32
#define INW  64
#define OUTW 64
#define NN   128
#define WD   64
#define RR   4
#define HH   256
#define IFSZ 471
#define CINW (INW + RR*WD)   // 320
#define CLIPV 20.0f
#define EPSV  1e-6f

// interface vector offsets (cumsum of IF_SIZES)
#define OFF_RK   0     // read keys   4*64
#define OFF_RSTR 256   // read strengths 4
#define OFF_WK   260   // write key   64
#define OFF_WSTR 324   // write strength 1
#define OFF_ER   325   // erase       64
#define OFF_WV   389   // write vec   64
#define OFF_FG   453   // free gates  4
#define OFF_AG   457   // alloc gate  1
#define OFF_WG   458   // write gate  1
#define OFF_MD   459   // modes       4*3

// scal[] slots
#define S_WSTR 0
#define S_AG   1
#define S_WG   2
#define S_KNW  3
#define S_WSUM 4
#define S_RSTR 8   // +r
#define S_FG   12  // +r
#define S_KNR  16  // +r
#define S_BM   20  // +r
#define S_FM   24  // +r
#define S_CM   28  // +r

#define SMEM_FLOATS 31224
#define SMEM_BYTES  (SMEM_FLOATS * 4)

__device__ __forceinline__ float sigf(float x){ return 1.0f/(1.0f+expf(-x)); }
__device__ __forceinline__ float sofp(float x){ return fmaxf(x,0.0f)+log1pf(expf(-fabsf(x))); }

__device__ __forceinline__ float wredSum(float v){
  #pragma unroll
  for (int m=32;m>0;m>>=1) v += __shfl_xor(v,m,64);
  return v;
}
__device__ __forceinline__ float wredMax(float v){
  #pragma unroll
  for (int m=32;m>0;m>>=1) v = fmaxf(v,__shfl_xor(v,m,64));
  return v;
}

extern "C" __global__ __launch_bounds__(1024, 1)
void dnc_fused(const float* __restrict__ inputs,
               const float* __restrict__ Wx0, const float* __restrict__ Wh0, const float* __restrict__ b0,
               const float* __restrict__ Wx1, const float* __restrict__ Wh1, const float* __restrict__ b1,
               const float* __restrict__ Wif, const float* __restrict__ bif,
               const float* __restrict__ Wout, const float* __restrict__ bout,
               float* __restrict__ out)
{
  const int b    = blockIdx.x;
  const int tid  = threadIdx.x;
  const int lane = tid & 63;
  const int wid  = tid >> 6;

  extern __shared__ float sm[];
  float* Ms  = sm;            // [128][65] memory, padded (stride 65 -> conflict-free)
  float* Ls  = sm + 8320;     // [128][129] link, padded
  float* h0s = sm + 24832;    // 256
  float* c0s = sm + 25088;    // 256
  float* h1s = sm + 25344;    // 256
  float* c1s = sm + 25600;    // 256
  float* gts = sm + 25856;    // 1024 gate scratch
  float* cin = sm + 26880;    // 320 ctrl_in
  float* ctl = sm + 27200;    // 256 clipped h1
  float* ifc = sm + 27456;    // 472 interface vector
  float* rws = sm + 27928;    // 4*128 read weights
  float* fwds= sm + 28440;    // 4*128
  float* bwds= sm + 28952;    // 4*128
  float* wws = sm + 29464;    // 128 write weights
  float* prc = sm + 29592;    // 128 precedence
  float* usg = sm + 29720;    // 128 usage
  float* u2  = sm + 29848;    // 128 eps-adjusted usage
  float* wcs = sm + 29976;    // 128 write content weights
  float* rcs = sm + 30104;    // 4*128 read content weights
  float* mno = sm + 30616;    // 128 ||M_n||
  float* rds = sm + 30744;    // 4*64 reads
  float* ers = sm + 31000;    // 64 erase (sigmoid)
  float* wvs = sm + 31064;    // 64 write vector
  float* sc  = sm + 31128;    // 64 reduction scratch
  float* scal= sm + 31192;    // 32 scalars

  // ---- zero-init all state ----
  for (int i = tid; i < NN*65;  i += 1024) Ms[i] = 0.0f;
  for (int i = tid; i < NN*129; i += 1024) Ls[i] = 0.0f;
  if (tid < HH){ h0s[tid]=0.f; c0s[tid]=0.f; h1s[tid]=0.f; c1s[tid]=0.f; }
  if (tid < RR*NN) rws[tid]=0.f;
  if (tid < NN){ wws[tid]=0.f; prc[tid]=0.f; usg[tid]=0.f; }
  if (tid < RR*WD) rds[tid]=0.f;
  __syncthreads();

  for (int t=0; t<TT; ++t){
    // ---- A: build ctrl_in = [x_t, reads] ----
    if (tid < INW)            cin[tid] = inputs[(t*BB + b)*INW + tid];
    else if (tid < CINW)      cin[tid] = rds[tid - INW];
    __syncthreads();

    // ---- B: LSTM0 gates (all 1024 threads, 1 column each) ----
    {
      float acc = b0[tid];
      const float* w = Wx0 + tid;
      #pragma unroll 8
      for (int k=0;k<CINW;k++) acc += cin[k]*w[k*1024];
      const float* w2 = Wh0 + tid;
      #pragma unroll 8
      for (int k=0;k<HH;k++)   acc += h0s[k]*w2[k*1024];
      gts[tid]=acc;
    }
    __syncthreads();
    // ---- C: LSTM0 cell update ----
    if (tid < HH){
      float i_=sigf(gts[tid]), f_=sigf(gts[HH+tid]);
      float g_=tanhf(gts[2*HH+tid]), o_=sigf(gts[3*HH+tid]);
      float c = f_*c0s[tid] + i_*g_;
      c0s[tid]=c; h0s[tid]=o_*tanhf(c);
    }
    __syncthreads();
    // ---- D: LSTM1 gates ----
    {
      float acc = b1[tid];
      const float* w = Wx1 + tid;
      #pragma unroll 8
      for (int k=0;k<HH;k++) acc += h0s[k]*w[k*1024];
      const float* w2 = Wh1 + tid;
      #pragma unroll 8
      for (int k=0;k<HH;k++) acc += h1s[k]*w2[k*1024];
      gts[tid]=acc;
    }
    __syncthreads();
    if (tid < HH){
      float i_=sigf(gts[tid]), f_=sigf(gts[HH+tid]);
      float g_=tanhf(gts[2*HH+tid]), o_=sigf(gts[3*HH+tid]);
      float c = f_*c1s[tid] + i_*g_;
      c1s[tid]=c;
      float h = o_*tanhf(c);
      h1s[tid]=h;
      ctl[tid]=fminf(CLIPV, fmaxf(-CLIPV, h));
    }
    __syncthreads();
    // ---- E: interface vector ----
    if (tid < IFSZ){
      float acc = bif[tid];
      const float* w = Wif + tid;
      #pragma unroll 8
      for (int k=0;k<HH;k++) acc += ctl[k]*w[k*IFSZ];
      ifc[tid]=acc;
    }
    __syncthreads();
    // ---- F: derived scalars + mnorm(old M) + key norms (disjoint thread ranges) ----
    if (tid < RR){
      scal[S_RSTR+tid]=1.0f+sofp(ifc[OFF_RSTR+tid]);
      scal[S_FG+tid]  =sigf(ifc[OFF_FG+tid]);
      float m0=ifc[OFF_MD+tid*3], m1=ifc[OFF_MD+tid*3+1], m2=ifc[OFF_MD+tid*3+2];
      float mx=fmaxf(m0,fmaxf(m1,m2));
      float e0=expf(m0-mx), e1=expf(m1-mx), e2=expf(m2-mx);
      float s=e0+e1+e2;
      scal[S_BM+tid]=e0/s; scal[S_FM+tid]=e1/s; scal[S_CM+tid]=e2/s;
    }
    if (tid == 4) scal[S_WSTR]=1.0f+sofp(ifc[OFF_WSTR]);
    if (tid == 5) scal[S_AG]=sigf(ifc[OFF_AG]);
    if (tid == 6) scal[S_WG]=sigf(ifc[OFF_WG]);
    if (tid >= 64 && tid < 128){
      int d=tid-64;
      ers[d]=sigf(ifc[OFF_ER+d]);
      wvs[d]=ifc[OFF_WV+d];
    }
    if (tid >= 128 && tid < 256){     // mnorm of OLD M (for write content weights)
      int n=tid-128; float s=0.f;
      #pragma unroll 8
      for (int d=0;d<WD;d++){ float v=Ms[n*65+d]; s+=v*v; }
      mno[n]=sqrtf(s);
    }
    if (wid == 8){                    // ||write key||
      float v=ifc[OFF_WK+lane]; float s=wredSum(v*v);
      if (lane==0) scal[S_KNW]=sqrtf(s);
    }
    if (wid >= 10 && wid < 14){       // ||read key r||
      int r=wid-10; float v=ifc[OFF_RK+r*WD+lane]; float s=wredSum(v*v);
      if (lane==0) scal[S_KNR+r]=sqrtf(s);
    }
    __syncthreads();
    // ---- G: write content weights (cosine sim softmax over N) ----
    if (tid < NN){
      float dot=0.f;
      #pragma unroll 8
      for (int d=0;d<WD;d++) dot += ifc[OFF_WK+d]*Ms[tid*65+d];
      float sim = dot/(scal[S_KNW]*mno[tid]+EPSV);
      wcs[tid]=sim*scal[S_WSTR];
    }
    __syncthreads();
    if (tid < NN){ float mx=wredMax(wcs[tid]); if(lane==0) sc[wid]=mx; }
    __syncthreads();
    if (tid < NN){
      float mx=fmaxf(sc[0],sc[1]);
      float e=expf(wcs[tid]-mx);
      wcs[tid]=e;
      float s=wredSum(e); if(lane==0) sc[2+wid]=s;
    }
    __syncthreads();
    if (tid < NN) wcs[tid]=wcs[tid]/(sc[2]+sc[3]);
    __syncthreads();
    // ---- H: usage update + allocation (stable-sort semantics via masked product) + ww ----
    if (tid < NN){
      float cw = wws[tid];                       // NW=1: 1-prod(1-ww) = ww
      float u  = usg[tid] + (1.0f-usg[tid])*cw;
      float psi=1.0f;
      #pragma unroll
      for (int r=0;r<RR;r++) psi *= 1.0f - scal[S_FG+r]*rws[r*NN+tid];
      float us = u*psi;
      usg[tid]=us;
      u2[tid] = EPSV + (1.0f-EPSV)*us;
    }
    __syncthreads();
    if (tid < NN){
      float ui=u2[tid]; float p=1.0f;
      for (int j=0;j<NN;j++){
        float uj=u2[j];
        bool take = (uj<ui) || (uj==ui && j<tid);  // stable argsort tie-break
        p *= take ? uj : 1.0f;
      }
      float a = (1.0f-ui)*p;
      float wwn = scal[S_WG]*( scal[S_AG]*a + (1.0f-scal[S_AG])*wcs[tid] );
      wws[tid]=wwn;
      float s=wredSum(wwn); if(lane==0) sc[wid]=s;
    }
    __syncthreads();
    if (tid==0) scal[S_WSUM]=sc[0]+sc[1];
    __syncthreads();
    // ---- I: memory erase/add + link update (uses old prec) ----
    #pragma unroll
    for (int i=0;i<8;i++){
      int el=tid+i*1024, n=el>>6, d=el&63;
      float w=wws[n];
      Ms[n*65+d] = Ms[n*65+d]*(1.0f - w*ers[d]) + w*wvs[d];
    }
    #pragma unroll
    for (int i=0;i<16;i++){
      int el=tid+i*1024, li=el>>7, lj=el&127;
      float v = (li==lj) ? 0.0f
              : (1.0f - wws[li] - wws[lj])*Ls[li*129+lj] + wws[li]*prc[lj];
      Ls[li*129+lj]=v;
    }
    __syncthreads();
    // prec update + mnorm of NEW M (disjoint ranges)
    if (tid < NN) prc[tid] = (1.0f - scal[S_WSUM])*prc[tid] + wws[tid];
    if (tid >= 128 && tid < 256){
      int n=tid-128; float s=0.f;
      #pragma unroll 8
      for (int d=0;d<WD;d++){ float v=Ms[n*65+d]; s+=v*v; }
      mno[n]=sqrtf(s);
    }
    __syncthreads();
    // ---- L: read content weights (4 heads in parallel) ----
    if (tid < RR*NN){
      int r=tid>>7, n=tid&127;
      float dot=0.f;
      #pragma unroll 8
      for (int d=0;d<WD;d++) dot += ifc[OFF_RK+r*WD+d]*Ms[n*65+d];
      float sim = dot/(scal[S_KNR+r]*mno[n]+EPSV);
      rcs[tid]=sim*scal[S_RSTR+r];
    }
    __syncthreads();
    if (tid < RR*NN){ float mx=wredMax(rcs[tid]); if(lane==0) sc[wid]=mx; }
    __syncthreads();
    if (tid < RR*NN){
      int r=tid>>7;
      float mx=fmaxf(sc[r*2],sc[r*2+1]);
      float e=expf(rcs[tid]-mx);
      rcs[tid]=e;
      float s=wredSum(e); if(lane==0) sc[8+wid]=s;
    }
    __syncthreads();
    if (tid < RR*NN){
      int r=tid>>7;
      rcs[tid]=rcs[tid]/(sc[8+r*2]+sc[9+r*2]);
    }
    __syncthreads();
    // ---- M: fwd/bwd link matvecs (new link, old rw) then rw update ----
    if (tid < RR*NN){
      int r=tid>>7, i=tid&127;
      float f=0.f, bw=0.f;
      const float* rwr = rws + r*NN;
      #pragma unroll 4
      for (int j=0;j<NN;j++){
        float rv=rwr[j];
        f  += Ls[i*129+j]*rv;   // stride-129 across lanes: conflict-free
        bw += Ls[j*129+i]*rv;   // contiguous across lanes
      }
      fwds[tid]=f; bwds[tid]=bw;
    }
    __syncthreads();
    if (tid < RR*NN){
      int r=tid>>7;
      rws[tid] = scal[S_BM+r]*bwds[tid] + scal[S_CM+r]*rcs[tid] + scal[S_FM+r]*fwds[tid];
    }
    __syncthreads();
    // ---- N: reads = rw @ M ----
    if (tid < RR*WD){
      int r=tid>>6, d=tid&63;
      float s=0.f;
      #pragma unroll 8
      for (int n=0;n<NN;n++) s += rws[r*NN+n]*Ms[n*65+d];
      rds[tid]=s;
    }
    __syncthreads();
    // ---- O: output projection ----
    if (tid < OUTW){
      float acc = bout[tid];
      const float* w = Wout + tid;
      #pragma unroll 8
      for (int k=0;k<HH;k++)    acc += ctl[k]*w[k*OUTW];
      #pragma unroll 8
      for (int k=0;k<RR*WD;k++) acc += rds[k]*w[(HH+k)*OUTW];
      out[(t*BB+b)*OUTW+tid] = fminf(CLIPV, fmaxf(-CLIPV, acc));
    }
    __syncthreads();
  }
}

extern "C" void kernel_launch(void* const* d_in, const int* in_sizes, int n_in,
                              void* d_out, int out_size, void* d_ws, size_t ws_size,
                              hipStream_t stream)
{
  const float* inputs=(const float*)d_in[0];
  const float* Wx0   =(const float*)d_in[1];
  const float* Wh0   =(const float*)d_in[2];
  const float* b0    =(const float*)d_in[3];
  const float* Wx1   =(const float*)d_in[4];
  const float* Wh1   =(const float*)d_in[5];
  const float* b1    =(const float*)d_in[6];
  const float* Wif   =(const float*)d_in[7];
  const float* bif   =(const float*)d_in[8];
  const float* Wout  =(const float*)d_in[9];
  const float* bout  =(const float*)d_in[10];
  float* out = (float*)d_out;

  // dynamic LDS ~122 KB (>64 KB default) — raise the cap; idempotent, capture-safe
  hipFuncSetAttribute((const void*)dnc_fused,
                      hipFuncAttributeMaxDynamicSharedMemorySize, SMEM_BYTES);

  dnc_fused<<<dim3(BB), dim3(1024), SMEM_BYTES, stream>>>(
      inputs, Wx0, Wh0, b0, Wx1, Wh1, b1, Wif, bif, Wout, bout, out);
}

// Round 2
// 7625.528 us; speedup vs baseline: 3.8905x; 3.8905x over previous
//
#include <hip/hip_runtime.h>
#include <math.h>

// DNC forward, fully fused: 1 block per batch element, T-loop inside kernel,
// all recurrent state in LDS. fp32 end-to-end.
// R1: K-split (4-way) + float4 weight loads for the big matvecs; two-stage
// LDS reduction fused into the cell updates. Cuts per-thread serial load
// rounds ~16x on LSTM0/LSTM1 (latency-bound critical path).

#define TT   64
#define BB   32
#define INW  64
#define OUTW 64
#define NN   128
#define WD   64
#define RR   4
#define HH   256
#define IFSZ 471
#define CINW (INW + RR*WD)   // 320
#define CLIPV 20.0f
#define EPSV  1e-6f

// interface vector offsets (cumsum of IF_SIZES)
#define OFF_RK   0     // read keys   4*64
#define OFF_RSTR 256   // read strengths 4
#define OFF_WK   260   // write key   64
#define OFF_WSTR 324   // write strength 1
#define OFF_ER   325   // erase       64
#define OFF_WV   389   // write vec   64
#define OFF_FG   453   // free gates  4
#define OFF_AG   457   // alloc gate  1
#define OFF_WG   458   // write gate  1
#define OFF_MD   459   // modes       4*3

// scal[] slots
#define S_WSTR 0
#define S_AG   1
#define S_WG   2
#define S_KNW  3
#define S_WSUM 4
#define S_RSTR 8   // +r
#define S_FG   12  // +r
#define S_KNR  16  // +r
#define S_BM   20  // +r
#define S_FM   24  // +r
#define S_CM   28  // +r

#define SMEM_FLOATS 35320
#define SMEM_BYTES  (SMEM_FLOATS * 4)

__device__ __forceinline__ float sigf(float x){ return 1.0f/(1.0f+expf(-x)); }
__device__ __forceinline__ float sofp(float x){ return fmaxf(x,0.0f)+log1pf(expf(-fabsf(x))); }

__device__ __forceinline__ float wredSum(float v){
  #pragma unroll
  for (int m=32;m>0;m>>=1) v += __shfl_xor(v,m,64);
  return v;
}
__device__ __forceinline__ float wredMax(float v){
  #pragma unroll
  for (int m=32;m>0;m>>=1) v = fmaxf(v,__shfl_xor(v,m,64));
  return v;
}

extern "C" __global__ __launch_bounds__(1024, 1)
void dnc_fused(const float* __restrict__ inputs,
               const float* __restrict__ Wx0, const float* __restrict__ Wh0, const float* __restrict__ b0,
               const float* __restrict__ Wx1, const float* __restrict__ Wh1, const float* __restrict__ b1,
               const float* __restrict__ Wif, const float* __restrict__ bif,
               const float* __restrict__ Wout, const float* __restrict__ bout,
               float* __restrict__ out)
{
  const int b    = blockIdx.x;
  const int tid  = threadIdx.x;
  const int lane = tid & 63;
  const int wid  = tid >> 6;

  extern __shared__ float sm[];
  float* Ms  = sm;            // [128][65] memory, padded (stride 65 -> conflict-free)
  float* Ls  = sm + 8320;     // [128][129] link, padded
  float* h0s = sm + 24832;    // 256
  float* c0s = sm + 25088;    // 256
  float* h1s = sm + 25344;    // 256
  float* c1s = sm + 25600;    // 256
  float* gts = sm + 25856;    // 1024 (unused scratch, kept for layout stability)
  float* cin = sm + 26880;    // 320 ctrl_in
  float* ctl = sm + 27200;    // 256 clipped h1
  float* ifc = sm + 27456;    // 472 interface vector
  float* rws = sm + 27928;    // 4*128 read weights
  float* fwds= sm + 28440;    // 4*128
  float* bwds= sm + 28952;    // 4*128
  float* wws = sm + 29464;    // 128 write weights
  float* prc = sm + 29592;    // 128 precedence
  float* usg = sm + 29720;    // 128 usage
  float* u2  = sm + 29848;    // 128 eps-adjusted usage
  float* wcs = sm + 29976;    // 128 write content weights
  float* rcs = sm + 30104;    // 4*128 read content weights
  float* mno = sm + 30616;    // 128 ||M_n||
  float* rds = sm + 30744;    // 4*64 reads
  float* ers = sm + 31000;    // 64 erase (sigmoid)
  float* wvs = sm + 31064;    // 64 write vector
  float* sc  = sm + 31128;    // 64 reduction scratch
  float* scal= sm + 31192;    // 32 scalars
  float* part= sm + 31224;    // 4096 K-split partial sums

  (void)gts;

  // ---- zero-init all state ----
  for (int i = tid; i < NN*65;  i += 1024) Ms[i] = 0.0f;
  for (int i = tid; i < NN*129; i += 1024) Ls[i] = 0.0f;
  if (tid < HH){ h0s[tid]=0.f; c0s[tid]=0.f; h1s[tid]=0.f; c1s[tid]=0.f; }
  if (tid < RR*NN) rws[tid]=0.f;
  if (tid < NN){ wws[tid]=0.f; prc[tid]=0.f; usg[tid]=0.f; }
  if (tid < RR*WD) rds[tid]=0.f;
  __syncthreads();

  const int kq4 = tid >> 8;    // 0..3   (4-way K split)
  const int c4  = tid & 255;   // column group: cols 4*c4 .. 4*c4+3

  for (int t=0; t<TT; ++t){
    // ---- A: build ctrl_in = [x_t, reads] ----
    if (tid < INW)            cin[tid] = inputs[(t*BB + b)*INW + tid];
    else if (tid < CINW)      cin[tid] = rds[tid - INW];
    __syncthreads();

    // ---- B: LSTM0 gates, K-split + float4 ----
    {
      float a0=0.f,a1=0.f,a2=0.f,a3=0.f;
      { // x part: K=320, 80 per kq
        const float4* Wp = reinterpret_cast<const float4*>(Wx0) + (kq4*80)*256 + c4;
        const float*  xp = cin + kq4*80;
        #pragma unroll 8
        for (int k=0;k<80;k++){
          float4 w4 = Wp[k*256];
          float  x  = xp[k];
          a0 += x*w4.x; a1 += x*w4.y; a2 += x*w4.z; a3 += x*w4.w;
        }
      }
      { // h part: K=256, 64 per kq
        const float4* Wp = reinterpret_cast<const float4*>(Wh0) + (kq4*64)*256 + c4;
        const float*  xp = h0s + kq4*64;
        #pragma unroll 8
        for (int k=0;k<64;k++){
          float4 w4 = Wp[k*256];
          float  x  = xp[k];
          a0 += x*w4.x; a1 += x*w4.y; a2 += x*w4.z; a3 += x*w4.w;
        }
      }
      *reinterpret_cast<float4*>(part + kq4*1024 + 4*c4) = make_float4(a0,a1,a2,a3);
    }
    __syncthreads();
    // ---- C: LSTM0 cell update (fused kq-reduction) ----
    if (tid < HH){
      const int j = tid;
      float gi=b0[j], gf=b0[HH+j], gg=b0[2*HH+j], go=b0[3*HH+j];
      #pragma unroll
      for (int q=0;q<4;q++){
        const float* pp = part + q*1024;
        gi += pp[j]; gf += pp[HH+j]; gg += pp[2*HH+j]; go += pp[3*HH+j];
      }
      float i_=sigf(gi), f_=sigf(gf), g_=tanhf(gg), o_=sigf(go);
      float c = f_*c0s[j] + i_*g_;
      c0s[j]=c; h0s[j]=o_*tanhf(c);
    }
    __syncthreads();
    // ---- D: LSTM1 gates, K-split + float4 ----
    {
      float a0=0.f,a1=0.f,a2=0.f,a3=0.f;
      {
        const float4* Wp = reinterpret_cast<const float4*>(Wx1) + (kq4*64)*256 + c4;
        const float*  xp = h0s + kq4*64;
        #pragma unroll 8
        for (int k=0;k<64;k++){
          float4 w4 = Wp[k*256];
          float  x  = xp[k];
          a0 += x*w4.x; a1 += x*w4.y; a2 += x*w4.z; a3 += x*w4.w;
        }
      }
      {
        const float4* Wp = reinterpret_cast<const float4*>(Wh1) + (kq4*64)*256 + c4;
        const float*  xp = h1s + kq4*64;
        #pragma unroll 8
        for (int k=0;k<64;k++){
          float4 w4 = Wp[k*256];
          float  x  = xp[k];
          a0 += x*w4.x; a1 += x*w4.y; a2 += x*w4.z; a3 += x*w4.w;
        }
      }
      *reinterpret_cast<float4*>(part + kq4*1024 + 4*c4) = make_float4(a0,a1,a2,a3);
    }
    __syncthreads();
    // ---- LSTM1 cell update + clip ----
    if (tid < HH){
      const int j = tid;
      float gi=b1[j], gf=b1[HH+j], gg=b1[2*HH+j], go=b1[3*HH+j];
      #pragma unroll
      for (int q=0;q<4;q++){
        const float* pp = part + q*1024;
        gi += pp[j]; gf += pp[HH+j]; gg += pp[2*HH+j]; go += pp[3*HH+j];
      }
      float i_=sigf(gi), f_=sigf(gf), g_=tanhf(gg), o_=sigf(go);
      float c = f_*c1s[j] + i_*g_;
      c1s[j]=c;
      float h = o_*tanhf(c);
      h1s[j]=h;
      ctl[j]=fminf(CLIPV, fmaxf(-CLIPV, h));
    }
    __syncthreads();
    // ---- E: interface vector, K-split (scalar loads, stride 471) ----
    {
      const int c2 = c4 + 256;
      const bool has2 = (c2 < IFSZ);
      float a0=0.f, a1=0.f;
      const float* Wp = Wif + (kq4*64)*IFSZ;
      const float* xp = ctl + kq4*64;
      #pragma unroll 8
      for (int k=0;k<64;k++){
        float x = xp[k];
        a0 += x*Wp[k*IFSZ + c4];
        if (has2) a1 += x*Wp[k*IFSZ + c2];
      }
      part[kq4*512 + c4] = a0;
      part[kq4*512 + c2] = a1;
    }
    __syncthreads();
    if (tid < IFSZ){
      float acc = bif[tid];
      #pragma unroll
      for (int q=0;q<4;q++) acc += part[q*512 + tid];
      ifc[tid]=acc;
    }
    __syncthreads();
    // ---- F: derived scalars + mnorm(old M) + key norms (disjoint thread ranges) ----
    if (tid < RR){
      scal[S_RSTR+tid]=1.0f+sofp(ifc[OFF_RSTR+tid]);
      scal[S_FG+tid]  =sigf(ifc[OFF_FG+tid]);
      float m0=ifc[OFF_MD+tid*3], m1=ifc[OFF_MD+tid*3+1], m2=ifc[OFF_MD+tid*3+2];
      float mx=fmaxf(m0,fmaxf(m1,m2));
      float e0=expf(m0-mx), e1=expf(m1-mx), e2=expf(m2-mx);
      float s=e0+e1+e2;
      scal[S_BM+tid]=e0/s; scal[S_FM+tid]=e1/s; scal[S_CM+tid]=e2/s;
    }
    if (tid == 4) scal[S_WSTR]=1.0f+sofp(ifc[OFF_WSTR]);
    if (tid == 5) scal[S_AG]=sigf(ifc[OFF_AG]);
    if (tid == 6) scal[S_WG]=sigf(ifc[OFF_WG]);
    if (tid >= 64 && tid < 128){
      int d=tid-64;
      ers[d]=sigf(ifc[OFF_ER+d]);
      wvs[d]=ifc[OFF_WV+d];
    }
    if (tid >= 128 && tid < 256){     // mnorm of OLD M (for write content weights)
      int n=tid-128; float s=0.f;
      #pragma unroll 8
      for (int d=0;d<WD;d++){ float v=Ms[n*65+d]; s+=v*v; }
      mno[n]=sqrtf(s);
    }
    if (wid == 8){                    // ||write key||
      float v=ifc[OFF_WK+lane]; float s=wredSum(v*v);
      if (lane==0) scal[S_KNW]=sqrtf(s);
    }
    if (wid >= 10 && wid < 14){       // ||read key r||
      int r=wid-10; float v=ifc[OFF_RK+r*WD+lane]; float s=wredSum(v*v);
      if (lane==0) scal[S_KNR+r]=sqrtf(s);
    }
    __syncthreads();
    // ---- G: write content weights (cosine sim softmax over N) ----
    if (tid < NN){
      float dot=0.f;
      #pragma unroll 8
      for (int d=0;d<WD;d++) dot += ifc[OFF_WK+d]*Ms[tid*65+d];
      float sim = dot/(scal[S_KNW]*mno[tid]+EPSV);
      wcs[tid]=sim*scal[S_WSTR];
    }
    __syncthreads();
    if (tid < NN){ float mx=wredMax(wcs[tid]); if(lane==0) sc[wid]=mx; }
    __syncthreads();
    if (tid < NN){
      float mx=fmaxf(sc[0],sc[1]);
      float e=expf(wcs[tid]-mx);
      wcs[tid]=e;
      float s=wredSum(e); if(lane==0) sc[2+wid]=s;
    }
    __syncthreads();
    if (tid < NN) wcs[tid]=wcs[tid]/(sc[2]+sc[3]);
    __syncthreads();
    // ---- H: usage update + allocation (stable-sort semantics via masked product) + ww ----
    if (tid < NN){
      float cw = wws[tid];                       // NW=1: 1-prod(1-ww) = ww
      float u  = usg[tid] + (1.0f-usg[tid])*cw;
      float psi=1.0f;
      #pragma unroll
      for (int r=0;r<RR;r++) psi *= 1.0f - scal[S_FG+r]*rws[r*NN+tid];
      float us = u*psi;
      usg[tid]=us;
      u2[tid] = EPSV + (1.0f-EPSV)*us;
    }
    __syncthreads();
    if (tid < NN){
      float ui=u2[tid]; float p=1.0f;
      for (int j=0;j<NN;j++){
        float uj=u2[j];
        bool take = (uj<ui) || (uj==ui && j<tid);  // stable argsort tie-break
        p *= take ? uj : 1.0f;
      }
      float a = (1.0f-ui)*p;
      float wwn = scal[S_WG]*( scal[S_AG]*a + (1.0f-scal[S_AG])*wcs[tid] );
      wws[tid]=wwn;
      float s=wredSum(wwn); if(lane==0) sc[wid]=s;
    }
    __syncthreads();
    if (tid==0) scal[S_WSUM]=sc[0]+sc[1];
    __syncthreads();
    // ---- I: memory erase/add + link update (uses old prec) ----
    #pragma unroll
    for (int i=0;i<8;i++){
      int el=tid+i*1024, n=el>>6, d=el&63;
      float w=wws[n];
      Ms[n*65+d] = Ms[n*65+d]*(1.0f - w*ers[d]) + w*wvs[d];
    }
    #pragma unroll
    for (int i=0;i<16;i++){
      int el=tid+i*1024, li=el>>7, lj=el&127;
      float v = (li==lj) ? 0.0f
              : (1.0f - wws[li] - wws[lj])*Ls[li*129+lj] + wws[li]*prc[lj];
      Ls[li*129+lj]=v;
    }
    __syncthreads();
    // prec update + mnorm of NEW M (disjoint ranges)
    if (tid < NN) prc[tid] = (1.0f - scal[S_WSUM])*prc[tid] + wws[tid];
    if (tid >= 128 && tid < 256){
      int n=tid-128; float s=0.f;
      #pragma unroll 8
      for (int d=0;d<WD;d++){ float v=Ms[n*65+d]; s+=v*v; }
      mno[n]=sqrtf(s);
    }
    __syncthreads();
    // ---- L: read content weights (4 heads in parallel) ----
    if (tid < RR*NN){
      int r=tid>>7, n=tid&127;
      float dot=0.f;
      #pragma unroll 8
      for (int d=0;d<WD;d++) dot += ifc[OFF_RK+r*WD+d]*Ms[n*65+d];
      float sim = dot/(scal[S_KNR+r]*mno[n]+EPSV);
      rcs[tid]=sim*scal[S_RSTR+r];
    }
    __syncthreads();
    if (tid < RR*NN){ float mx=wredMax(rcs[tid]); if(lane==0) sc[wid]=mx; }
    __syncthreads();
    if (tid < RR*NN){
      int r=tid>>7;
      float mx=fmaxf(sc[r*2],sc[r*2+1]);
      float e=expf(rcs[tid]-mx);
      rcs[tid]=e;
      float s=wredSum(e); if(lane==0) sc[8+wid]=s;
    }
    __syncthreads();
    if (tid < RR*NN){
      int r=tid>>7;
      rcs[tid]=rcs[tid]/(sc[8+r*2]+sc[9+r*2]);
    }
    __syncthreads();
    // ---- M: fwd/bwd link matvecs (new link, old rw) then rw update ----
    if (tid < RR*NN){
      int r=tid>>7, i=tid&127;
      float f=0.f, bw=0.f;
      const float* rwr = rws + r*NN;
      #pragma unroll 4
      for (int j=0;j<NN;j++){
        float rv=rwr[j];
        f  += Ls[i*129+j]*rv;   // stride-129 across lanes: conflict-free
        bw += Ls[j*129+i]*rv;   // contiguous across lanes
      }
      fwds[tid]=f; bwds[tid]=bw;
    }
    __syncthreads();
    if (tid < RR*NN){
      int r=tid>>7;
      rws[tid] = scal[S_BM+r]*bwds[tid] + scal[S_CM+r]*rcs[tid] + scal[S_FM+r]*fwds[tid];
    }
    __syncthreads();
    // ---- N: reads = rw @ M ----
    if (tid < RR*WD){
      int r=tid>>6, d=tid&63;
      float s=0.f;
      #pragma unroll 8
      for (int n=0;n<NN;n++) s += rws[r*NN+n]*Ms[n*65+d];
      rds[tid]=s;
    }
    __syncthreads();
    // ---- O: output projection, 16-way K-split ----
    {
      const int kq = tid >> 6;    // 0..15
      const int c  = tid & 63;
      const float* xbase = (kq < 8) ? (ctl + kq*32) : (rds + (kq-8)*32);
      const float* Wp = Wout + (kq*32)*OUTW + c;
      float a=0.f;
      #pragma unroll 8
      for (int k=0;k<32;k++) a += xbase[k]*Wp[k*OUTW];
      part[kq*64 + c] = a;
    }
    __syncthreads();
    if (tid < OUTW){
      float acc = bout[tid];
      #pragma unroll
      for (int q=0;q<16;q++) acc += part[q*64 + tid];
      out[(t*BB+b)*OUTW+tid] = fminf(CLIPV, fmaxf(-CLIPV, acc));
    }
    __syncthreads();
  }
}

extern "C" void kernel_launch(void* const* d_in, const int* in_sizes, int n_in,
                              void* d_out, int out_size, void* d_ws, size_t ws_size,
                              hipStream_t stream)
{
  const float* inputs=(const float*)d_in[0];
  const float* Wx0   =(const float*)d_in[1];
  const float* Wh0   =(const float*)d_in[2];
  const float* b0    =(const float*)d_in[3];
  const float* Wx1   =(const float*)d_in[4];
  const float* Wh1   =(const float*)d_in[5];
  const float* b1    =(const float*)d_in[6];
  const float* Wif   =(const float*)d_in[7];
  const float* bif   =(const float*)d_in[8];
  const float* Wout  =(const float*)d_in[9];
  const float* bout  =(const float*)d_in[10];
  float* out = (float*)d_out;

  // dynamic LDS ~138 KB (>64 KB default) — raise the cap; idempotent, capture-safe
  hipFuncSetAttribute((const void*)dnc_fused,
                      hipFuncAttributeMaxDynamicSharedMemorySize, SMEM_BYTES);

  dnc_fused<<<dim3(BB), dim3(1024), SMEM_BYTES, stream>>>(
      inputs, Wx0, Wh0, b0, Wx1, Wh1, b1, Wif, bif, Wout, bout, out);
}